// Round 11
// baseline (378.919 us; speedup 1.0000x reference)
//
#include <hip/hip_runtime.h>
#include <stdint.h>

#define S_LEN 2048
#define HIDDEN_ 2048
#define NH 16
#define QR 1536
#define KVR 512
#define DN 128
#define DR 64
#define DQK 192
#define DV 128
#define NQKV 2112   // QR + KVR + DR

// per-head tile-image strides (u16 units)
#define KT_STRIDE 6144   // 32 rows x 192 cols = 12288 B
#define VT_STRIDE 4096   // 128 d x 32 s      =  8192 B

typedef __attribute__((ext_vector_type(8))) short bf16x8;
typedef __attribute__((ext_vector_type(4))) float f32x4;
typedef __attribute__((ext_vector_type(4))) unsigned short u16x4;
typedef unsigned short u16;
typedef unsigned int u32;

#define GLOAD_LDS16(g, l)                                                      \
    __builtin_amdgcn_global_load_lds(                                          \
        (const __attribute__((address_space(1))) void*)(g),                    \
        (__attribute__((address_space(3))) void*)(l), 16, 0, 0)

__device__ inline float bf2f(u16 x) {
    union { u32 u; float f; } v; v.u = ((u32)x) << 16; return v.f;
}
__device__ inline u16 f2bf(float f) {
    union { float f; u32 u; } v; v.f = f;
    u32 u = v.u;
    return (u16)((u + 0x7fffu + ((u >> 16) & 1u)) >> 16);
}

// ---------------------------------------------------------------------------
// cvt of ALL 6 f32 tensors -> bf16, one launch, exact flattened grid.
// Blocks: 4096+3072+1152+4608+2048+4096 = 19072. All sizes %1024==0.
// ---------------------------------------------------------------------------
__global__ void cvt6(const float* __restrict__ s0, u16* __restrict__ d0, int n0,
                     const float* __restrict__ s1, u16* __restrict__ d1, int n1,
                     const float* __restrict__ s2, u16* __restrict__ d2, int n2,
                     const float* __restrict__ s3, u16* __restrict__ d3, int n3,
                     const float* __restrict__ s4, u16* __restrict__ d4, int n4,
                     const float* __restrict__ s5, u16* __restrict__ d5, int n5)
{
    const int b0 = n0 >> 10, b1 = n1 >> 10, b2 = n2 >> 10, b3 = n3 >> 10,
              b4 = n4 >> 10;
    int gid = blockIdx.x;
    const float* src; u16* dst; int base;
    if (gid < b0)                     { src = s0; dst = d0; base = gid; }
    else if ((gid -= b0) < b1)        { src = s1; dst = d1; base = gid; }
    else if ((gid -= b1) < b2)        { src = s2; dst = d2; base = gid; }
    else if ((gid -= b2) < b3)        { src = s3; dst = d3; base = gid; }
    else if ((gid -= b3) < b4)        { src = s4; dst = d4; base = gid; }
    else                              { src = s5; dst = d5; base = gid - b4; }
    int i = base * 1024 + threadIdx.x * 4;
    float4 v = *(const float4*)(src + i);
    u16x4 o;
    o[0] = f2bf(v.x); o[1] = f2bf(v.y); o[2] = f2bf(v.z); o[3] = f2bf(v.w);
    *(u16x4*)(dst + i) = o;
}

// ---------------------------------------------------------------------------
// GEMM body (round-8 proven version): C[M,N] = A[M,Kloop] @ B[N,Kloop]^T,
// f32 accumulate, bf16 or f32 out. 128x128 tile, BK=32, global_load_lds.
// ---------------------------------------------------------------------------
__device__ __forceinline__
void gemm_body(const u16* __restrict__ A, const u16* __restrict__ B,
               void* __restrict__ Cv, int M, int N, int Kloop, int ld,
               int out_f32, int bx, int by)
{
    __shared__ u16 sA[128 * 32];
    __shared__ u16 sB[128 * 32];
    const int tid  = threadIdx.x;
    const int wave = tid >> 6;
    const int lane = tid & 63;
    const int l16  = lane & 15;
    const int quad = lane >> 4;
    const int m_blk = by * 128;
    const int n_blk = bx * 128;
    const int wm = (wave >> 1) * 64;
    const int wn = (wave & 1) * 64;

    const f32x4 zero4 = {0.f, 0.f, 0.f, 0.f};
    f32x4 acc[4][4];
#pragma unroll
    for (int i = 0; i < 4; i++)
#pragma unroll
        for (int j = 0; j < 4; j++) acc[i][j] = zero4;

    const int srow = lane >> 2;
    const int scol = (lane & 3) * 8;

    for (int k0 = 0; k0 < Kloop; k0 += 32) {
        __syncthreads();
#pragma unroll
        for (int p = 0; p < 2; p++) {
            const int rbase = wave * 32 + p * 16;
            const int row = rbase + srow;
            const u16* ga = A + (size_t)(m_blk + row) * ld + k0 + scol;
            GLOAD_LDS16(ga, &sA[rbase * 32]);
            int brow = n_blk + row; if (brow >= N) brow = N - 1;
            const u16* gb = B + (size_t)brow * ld + k0 + scol;
            GLOAD_LDS16(gb, &sB[rbase * 32]);
        }
        __syncthreads();

        bf16x8 af[4], bfr[4];
#pragma unroll
        for (int i = 0; i < 4; i++)
            af[i] = *(const bf16x8*)(sA + (wm + i * 16 + l16) * 32 + quad * 8);
#pragma unroll
        for (int j = 0; j < 4; j++)
            bfr[j] = *(const bf16x8*)(sB + (wn + j * 16 + l16) * 32 + quad * 8);
#pragma unroll
        for (int i = 0; i < 4; i++)
#pragma unroll
            for (int j = 0; j < 4; j++)
                acc[i][j] = __builtin_amdgcn_mfma_f32_16x16x32_bf16(
                    af[i], bfr[j], acc[i][j], 0, 0, 0);
    }

#pragma unroll
    for (int i = 0; i < 4; i++)
#pragma unroll
        for (int j = 0; j < 4; j++)
#pragma unroll
            for (int r = 0; r < 4; r++) {
                int mrow = m_blk + wm + i * 16 + quad * 4 + r;
                int ncol = n_blk + wn + j * 16 + l16;
                if (ncol < N) {
                    if (out_f32)
                        ((float*)Cv)[(size_t)mrow * N + ncol] = acc[i][j][r];
                    else
                        ((u16*)Cv)[(size_t)mrow * N + ncol] = f2bf(acc[i][j][r]);
                }
            }
}

// Split-K x2 GEMM: z selects K-half, writes f32 partials C0 / C1.
__global__ __launch_bounds__(256, 3)
void gemm_splitk(const u16* __restrict__ A, const u16* __restrict__ B,
                 float* __restrict__ C0, float* __restrict__ C1,
                 int M, int N, int Kh, int ld)
{
    float* C = blockIdx.z ? C1 : C0;
    gemm_body(A + (size_t)blockIdx.z * Kh, B + (size_t)blockIdx.z * Kh,
              C, M, N, Kh, ld, 1, blockIdx.x, blockIdx.y);
}

// Two independent GEMMs in one launch (z selects).
__global__ __launch_bounds__(256, 3)
void gemm_dual(const u16* A0, const u16* B0, u16* C0, int M0, int N0, int K0,
               const u16* A1, const u16* B1, u16* C1, int M1, int N1, int K1)
{
    if (blockIdx.z == 0) {
        if ((int)blockIdx.x >= (N0 + 127) / 128) return;
        gemm_body(A0, B0, C0, M0, N0, K0, K0, 0, blockIdx.x, blockIdx.y);
    } else {
        gemm_body(A1, B1, C1, M1, N1, K1, K1, 0, blockIdx.x, blockIdx.y);
    }
}

// ---------------------------------------------------------------------------
// Merged RMSNorm over split-K f32 partials (combine fused in).
// ---------------------------------------------------------------------------
__global__ void rmsnorm2_k(const float* __restrict__ P0, const float* __restrict__ P1,
                           const float* __restrict__ W0, u16* __restrict__ Y0,
                           const float* __restrict__ W1, u16* __restrict__ Y1,
                           u16* __restrict__ kpe)
{
    const int row = blockIdx.x;
    const float* p0 = P0 + (size_t)row * NQKV;
    const float* p1 = P1 + (size_t)row * NQKV;
    __shared__ float xbuf[QR];
    __shared__ float red[4];
    int off, len; const float* W; u16* Y;
    if (blockIdx.y == 0) { off = 0;  len = QR;  W = W0; Y = Y0 + (size_t)row * QR;  }
    else                 { off = QR; len = KVR; W = W1; Y = Y1 + (size_t)row * KVR; }
    float ss = 0.f;
    for (int i = threadIdx.x; i < len; i += 256) {
        float v = p0[off + i] + p1[off + i];
        xbuf[i] = v;
        ss += v * v;
    }
#pragma unroll
    for (int o = 32; o; o >>= 1) ss += __shfl_down(ss, o, 64);
    if ((threadIdx.x & 63) == 0) red[threadIdx.x >> 6] = ss;
    __syncthreads();
    float tot = red[0] + red[1] + red[2] + red[3];
    float inv = 1.0f / sqrtf(tot / (float)len + 1e-6f);
    for (int i = threadIdx.x; i < len; i += 256)
        Y[i] = f2bf(W[i] * xbuf[i] * inv);
    if (blockIdx.y == 1 && threadIdx.x < DR) {
        int i = threadIdx.x;
        kpe[(size_t)row * DR + i] = f2bf(p0[QR + KVR + i] + p1[QR + KVR + i]);
    }
}

// ---------------------------------------------------------------------------
// FUSED repack: blocks 0..2047 do RoPE+repack (Q prescaled by scale/ln2,
// K tile images); blocks 2048..3071 do V transpose -> tile images.
// ---------------------------------------------------------------------------
__global__ void repack_fused(const u16* __restrict__ q,      // [S][H*192]
                             const u16* __restrict__ kvb,    // [S][H*256]
                             const u16* __restrict__ kpe_b,  // [S][64]
                             u16* __restrict__ Q, u16* __restrict__ Kf,
                             u16* __restrict__ Vt)
{
    __shared__ __align__(16) char smem[64 * 72 * 2];   // 9216 B, both branches
    const int bid = blockIdx.x;
    const int t = threadIdx.x;

    if (bid < S_LEN) {
        // ---------------- RoPE + Q/K repack ----------------
        float* cs = (float*)smem;            // [64]
        float* sn = cs + 64;                 // [64]
        u16* kpe_r = (u16*)(sn + 64);        // [64]
        const float QSC = 0.07216878364870323f * 1.4426950408889634f;
        const int s = bid;
        const float pos = (float)s;
        if (t < 64) {
            int jf = t & 31;
            float freq = powf(10000.f, -(float)(2 * jf) / 64.f);
            float ang = pos * freq;
            cs[t] = cosf(ang);
            sn[t] = sinf(ang);
        }
        __syncthreads();
        if (t < 64) {
            int j = t;
            float x = bf2f(kpe_b[(size_t)s * DR + j]);
            float other = (j < 32) ? -bf2f(kpe_b[(size_t)s * DR + j + 32])
                                   :  bf2f(kpe_b[(size_t)s * DR + j - 32]);
            kpe_r[j] = f2bf(x * cs[j] + other * sn[j]);
        }
        __syncthreads();

        for (int idx = t; idx < NH * 24; idx += 256) {
            const int h  = idx / 24;
            const int cg = idx % 24;
            const int d0v = cg * 8;
            const size_t qbase = (size_t)s * (NH * DQK) + h * DQK;
            bf16x8 qv, kv;
            if (d0v < DN) {
                bf16x8 qr = *(const bf16x8*)(q + qbase + d0v);
#pragma unroll
                for (int e = 0; e < 8; e++)
                    qv[e] = (short)f2bf(bf2f((u16)qr[e]) * QSC);
                kv = *(const bf16x8*)(kvb + (size_t)s * (NH * 256) + h * 256 + d0v);
            } else {
                const int j0 = d0v - DN;
#pragma unroll
                for (int e = 0; e < 8; e++) {
                    int j = j0 + e;
                    float x = bf2f(q[qbase + DN + j]);
                    float other = (j < 32) ? -bf2f(q[qbase + DN + j + 32])
                                           :  bf2f(q[qbase + DN + j - 32]);
                    qv[e] = (short)f2bf((x * cs[j] + other * sn[j]) * QSC);
                    kv[e] = (short)kpe_r[j];
                }
            }
            *(bf16x8*)&Q[((size_t)h * S_LEN + s) * DQK + d0v] = qv;
            const size_t koff = (size_t)(h * 64 + (s >> 5)) * KT_STRIDE
                              + (size_t)(cg * 32 + (s & 31)) * 8;
            *(bf16x8*)&Kf[koff] = kv;
        }
    } else {
        // ---------------- V transpose -> tile images ----------------
        u16 (*tile)[72] = (u16(*)[72])smem;
        const int r   = bid - S_LEN;          // 0..1023
        const int h   = r >> 6;
        const int rem = r & 63;
        const int s0  = (rem >> 1) * 64;
        const int d0  = (rem & 1) * 64;
#pragma unroll
        for (int p = 0; p < 2; p++) {
            int c = p * 256 + t;
            int rr = c >> 3, col = (c & 7) * 8;
            *(bf16x8*)&tile[rr][col] =
                *(const bf16x8*)&kvb[(size_t)(s0 + rr) * (NH * 256) + h * 256 + 128 + d0 + col];
        }
        __syncthreads();
#pragma unroll
        for (int p = 0; p < 2; p++) {
            int c = p * 256 + t;
            int dr = c >> 3, sc = (c & 7) * 8;
            bf16x8 v;
#pragma unroll
            for (int j = 0; j < 8; j++) v[j] = (short)tile[sc + j][dr];
            const int s_abs   = s0 + sc;
            const int kt      = s_abs >> 5;
            const int schunk  = (s_abs & 31) >> 3;
            const size_t voff = (size_t)(h * 64 + kt) * VT_STRIDE
                              + (size_t)(schunk * 128 + (d0 + dr)) * 8;
            *(bf16x8*)&Vt[voff] = v;
        }
    }
}

// ---------------------------------------------------------------------------
// Causal flash attention, ROUND 11: NO LDS STAGING. K/V tile images are
// L2-resident (1.3 MB/head x 2 heads/XCD < 4 MB L2, head-affinity swizzle;
// FETCH at unique-data floor proves no HBM re-reads). Fragments are read
// DIRECTLY from global (same addresses the LDS image had -> bit-identical).
// Removes the global_load_lds -> vmcnt(0)+barrier -> ds_read pipeline and
// ALL __syncthreads: waves run independently, each clamped at its own
// causal bound (also kills idle rounds for early waves).
// Round-4 balanced schedule kept: grid (48, NH), XCD head-affinity swizzle.
// Softmax in log2 domain; bpermute P-exchange; deferred row-sum; defer-max;
// v_cvt_pk_bf16_f32 packing; setprio around MFMA clusters.
// ---------------------------------------------------------------------------
__global__ __launch_bounds__(256, 3)
void mla_attn(const u16* __restrict__ Q, const u16* __restrict__ Kf,
              const u16* __restrict__ Vt, u16* __restrict__ attn,
              float* __restrict__ part)
{
    const int lin = blockIdx.x + 48 * blockIdx.y;
    const int h   = ((lin & 7) << 1) | ((lin >> 3) & 1);
    const int bx  = lin >> 4;

    int s, tb, te, cIdx; bool direct;
    if (bx < 16)      { s = 16 + bx; tb = 0;  te = 32;        cIdx = 0; direct = false; }
    else if (bx < 32) { s = bx;      tb = 32; te = 2 * s + 2; cIdx = 1; direct = false; }
    else              { s = 47 - bx; tb = 0;  te = 2 * s + 2; cIdx = 0; direct = true;  }

    const int wave  = threadIdx.x >> 6;
    const int lane  = threadIdx.x & 63;
    const int l16   = lane & 15;
    const int quad  = lane >> 4;
    const int q0    = s * 64 + wave * 16;
    const int qrow  = q0 + l16;

    // per-wave causal clamp (kt*32 <= q0+15)
    const int teW = min(te, (q0 + 15) / 32 + 1);

    const u16* Qh  = Q  + (size_t)h * S_LEN * DQK;
    const u16* Kh  = Kf + (size_t)h * 64 * KT_STRIDE;
    const u16* Vth = Vt + (size_t)h * 64 * VT_STRIDE;

    bf16x8 qf[6];
#pragma unroll
    for (int st = 0; st < 6; st++)
        qf[st] = *(const bf16x8*)(Qh + (size_t)qrow * DQK + st * 32 + quad * 8);

    const f32x4 zero4 = {0.f, 0.f, 0.f, 0.f};
    f32x4 oacc[8];
#pragma unroll
    for (int t = 0; t < 8; t++) oacc[t] = zero4;
    float mrow = -INFINITY, lrow = 0.f;   // log2 domain; lrow per-lane partial

    for (int kt = tb; kt < teW; kt++) {
        const int c0 = kt * 32;
        const u16* kp = Kh + (size_t)kt * KT_STRIDE;
        const u16* vp = Vth + (size_t)kt * VT_STRIDE;

        // V fragments issued first: their latency hides under the QK MFMAs.
        bf16x8 vfr[8];
#pragma unroll
        for (int t = 0; t < 8; t++)
            vfr[t] = *(const bf16x8*)(vp + (quad * 128 + t * 16 + l16) * 8);

        f32x4 s0 = zero4, s1 = zero4;
        __builtin_amdgcn_s_setprio(1);
#pragma unroll
        for (int st = 0; st < 6; st++) {
            bf16x8 k0 = *(const bf16x8*)(kp + ((st * 4 + quad) * 32 + l16) * 8);
            bf16x8 k1 = *(const bf16x8*)(kp + ((st * 4 + quad) * 32 + 16 + l16) * 8);
            s0 = __builtin_amdgcn_mfma_f32_16x16x32_bf16(k0, qf[st], s0, 0, 0, 0);
            s1 = __builtin_amdgcn_mfma_f32_16x16x32_bf16(k1, qf[st], s1, 0, 0, 0);
        }
        __builtin_amdgcn_s_setprio(0);

        const bool full = (c0 + 31 <= q0);
        float v0[4], v1[4];
#pragma unroll
        for (int r = 0; r < 4; r++) {
            v0[r] = s0[r];
            v1[r] = s1[r];
            if (!full) {
                if (c0 + quad * 4 + r > qrow)      v0[r] = -INFINITY;
                if (c0 + 16 + quad * 4 + r > qrow) v1[r] = -INFINITY;
            }
        }
        float lm = fmaxf(fmaxf(fmaxf(v0[0], v0[1]), fmaxf(v0[2], v0[3])),
                         fmaxf(fmaxf(v1[0], v1[1]), fmaxf(v1[2], v1[3])));
        lm = fmaxf(lm, __shfl_xor(lm, 16, 64));
        lm = fmaxf(lm, __shfl_xor(lm, 32, 64));

        // defer-max: skip rescale while tile max within +8/ln2 of m.
        float mref;
        if (__all(lm <= mrow + 11.5416f)) {
            mref = mrow;               // p <= 2^11.54 = e^8, bf16-safe
        } else {
            mref = fmaxf(mrow, lm);
            const float alpha = __builtin_amdgcn_exp2f(mrow - mref);
#pragma unroll
            for (int t = 0; t < 8; t++) oacc[t] *= alpha;
            lrow *= alpha;
            mrow = mref;
        }

        float p0[4], p1[4], rs = 0.f;
#pragma unroll
        for (int r = 0; r < 4; r++) {
            p0[r] = __builtin_amdgcn_exp2f(v0[r] - mref);
            p1[r] = __builtin_amdgcn_exp2f(v1[r] - mref);
            rs += p0[r] + p1[r];
        }
        lrow += rs;   // per-lane partial; reduced in epilogue

        // P pack via v_cvt_pk_bf16_f32 (RTNE = f2bf pair, 1 inst each)
        u32 A0, A1, B0, B1;
        asm("v_cvt_pk_bf16_f32 %0, %1, %2" : "=v"(A0) : "v"(p0[0]), "v"(p0[1]));
        asm("v_cvt_pk_bf16_f32 %0, %1, %2" : "=v"(A1) : "v"(p0[2]), "v"(p0[3]));
        asm("v_cvt_pk_bf16_f32 %0, %1, %2" : "=v"(B0) : "v"(p1[0]), "v"(p1[1]));
        asm("v_cvt_pk_bf16_f32 %0, %1, %2" : "=v"(B1) : "v"(p1[2]), "v"(p1[3]));
        const int a0 = (((quad & 1) << 5) + l16) << 2;
        const int a1 = a0 + 64;
        u32 Y0 = (u32)__builtin_amdgcn_ds_bpermute(a0, (int)A0);
        u32 Y1 = (u32)__builtin_amdgcn_ds_bpermute(a0, (int)A1);
        u32 Y2 = (u32)__builtin_amdgcn_ds_bpermute(a1, (int)A0);
        u32 Y3 = (u32)__builtin_amdgcn_ds_bpermute(a1, (int)A1);
        u32 Z0 = (u32)__builtin_amdgcn_ds_bpermute(a0, (int)B0);
        u32 Z1 = (u32)__builtin_amdgcn_ds_bpermute(a0, (int)B1);
        u32 Z2 = (u32)__builtin_amdgcn_ds_bpermute(a1, (int)B0);
        u32 Z3 = (u32)__builtin_amdgcn_ds_bpermute(a1, (int)B1);
        const bool useA = quad < 2;
        union { u32 w[4]; bf16x8 v; } pf;
        pf.w[0] = useA ? Y0 : Z0;
        pf.w[1] = useA ? Y1 : Z1;
        pf.w[2] = useA ? Y2 : Z2;
        pf.w[3] = useA ? Y3 : Z3;
        bf16x8 pfrag = pf.v;

        __builtin_amdgcn_s_setprio(1);
#pragma unroll
        for (int t = 0; t < 8; t++)
            oacc[t] = __builtin_amdgcn_mfma_f32_16x16x32_bf16(vfr[t], pfrag,
                                                              oacc[t], 0, 0, 0);
        __builtin_amdgcn_s_setprio(0);
    }

    // finish deferred row-sum (partials live per-quad)
    float lsum = lrow;
    lsum += __shfl_xor(lsum, 16, 64);
    lsum += __shfl_xor(lsum, 32, 64);

    if (direct) {
        const float linv = 1.0f / lsum;
#pragma unroll
        for (int t = 0; t < 8; t++) {
            u16x4 ov;
#pragma unroll
            for (int r = 0; r < 4; r++) ov[r] = f2bf(oacc[t][r] * linv);
            *(u16x4*)&attn[(size_t)qrow * (NH * DV) + h * DV + t * 16 + quad * 4] = ov;
        }
    } else {
        // partial record: 8320 f32 = O[64][128] ++ m[64] ++ l[64] (m in log2)
        float* pout = part + ((size_t)(h * 16 + (s - 16)) * 2 + cIdx) * 8320;
        const int rowl = wave * 16 + l16;
#pragma unroll
        for (int t = 0; t < 8; t++) {
            float4 ov = {oacc[t][0], oacc[t][1], oacc[t][2], oacc[t][3]};
            *(float4*)&pout[(size_t)rowl * 128 + t * 16 + quad * 4] = ov;
        }
        if (quad == 0) {
            pout[8192 + rowl] = mrow;
            pout[8256 + rowl] = lsum;
        }
    }
}

// ---------------------------------------------------------------------------
// Merge the two split-K partials for strips s=16..31 (m in log2 domain).
// ---------------------------------------------------------------------------
__global__ void attn_combine(const float* __restrict__ part, u16* __restrict__ attn)
{
    const int h = blockIdx.y, sIdx = blockIdx.x;
    const int s = 16 + sIdx;
    const float* p0 = part + ((size_t)(h * 16 + sIdx) * 2 + 0) * 8320;
    const float* p1 = p0 + 8320;
    for (int e = threadIdx.x; e < 8192; e += 256) {
        int row = e >> 7, d = e & 127;
        float m0 = p0[8192 + row], m1 = p1[8192 + row];
        float l0 = p0[8256 + row], l1 = p1[8256 + row];
        float M  = fmaxf(m0, m1);
        float w0 = __builtin_amdgcn_exp2f(m0 - M);
        float w1 = __builtin_amdgcn_exp2f(m1 - M);
        float o  = (w0 * p0[e] + w1 * p1[e]) / (w0 * l0 + w1 * l1);
        attn[(size_t)(s * 64 + row) * (NH * DV) + h * DV + d] = f2bf(o);
    }
}

// ---------------------------------------------------------------------------
// f32 a + b -> f32 out (final split-K combine for the output GEMM).
// ---------------------------------------------------------------------------
__global__ void addf2(const float* __restrict__ a, const float* __restrict__ b,
                      float* __restrict__ o, int n)
{
    int i = (blockIdx.x * 256 + threadIdx.x) * 4;
    if (i + 3 < n) {
        float4 va = *(const float4*)(a + i);
        float4 vb = *(const float4*)(b + i);
        float4 vo = {va.x + vb.x, va.y + vb.y, va.z + vb.z, va.w + vb.w};
        *(float4*)(o + i) = vo;
    }
}

// ---------------------------------------------------------------------------
extern "C" void kernel_launch(void* const* d_in, const int* in_sizes, int n_in,
                              void* d_out, int out_size, void* d_ws, size_t ws_size,
                              hipStream_t stream)
{
    const float* hid      = (const float*)d_in[0];
    // d_in[1] = position_ids (== arange(s)); sequence index used directly.
    const float* q_a_w    = (const float*)d_in[2];
    const float* q_a_ln_w = (const float*)d_in[3];
    const float* q_b_w    = (const float*)d_in[4];
    const float* kv_a_w   = (const float*)d_in[5];
    const float* kv_a_ln_w= (const float*)d_in[6];
    const float* kv_b_w   = (const float*)d_in[7];
    const float* o_w      = (const float*)d_in[8];

    char* base = (char*)d_ws;
    // -------- static (whole-call lifetime) --------
    u16* qkvaw_b = (u16*)(base + 0);          //  8,650,752  [2112,2048]
    u16* qbw_b   = (u16*)(base + 8650752);    //  9,437,184  [3072,1536]
    u16* kvbw_b  = (u16*)(base + 18087936);   //  4,194,304  [4096,512]
    u16* ow_b    = (u16*)(base + 22282240);   //  8,388,608  [2048,2048]
    u16* hid_b   = (u16*)(base + 30670848);   //  8,388,608  (dead after gemm1)
    // -------- dynamic (lifetime-overlaid) --------
    float* P0    = (float*)(base + 39059456); // 17,301,504  gemm1 K-half 0 (f32)
    float* P1    = (float*)(base + 56360960); // 17,301,504  gemm1 K-half 1 (f32)
    u16* q_n     = (u16*)(base + 73662464);   //  6,291,456  [2048,1536]
    u16* ckv     = (u16*)(base + 79953920);   //  2,097,152  [2048,512]
    u16* kpe_b   = (u16*)(base + 82051072);   //    262,144  [2048,64]
    u16* qb      = (u16*)(base + 82313216);   // 12,582,912  [2048,3072]
    u16* kvb     = (u16*)(base + 94896128);   // 16,777,216  [2048,4096]
    u16* Qb      = (u16*)(base + 39059456);   // 12,582,912  over dead P0
    u16* Kb      = (u16*)(base + 51642368);   // 12,582,912  tile images
    u16* Vtb     = (u16*)(base + 64225280);   //  8,388,608  tile images
    u16* attnb   = (u16*)(base + 72613888);   //  8,388,608  over dead q_n/ckv
    float* partb = (float*)(base + 94896128); // 17,039,360  over dead kvb
    float* PO0   = (float*)(base + 82313216); // 16,777,216  over dead qb/partb
    float* PO1   = (float*)(base + 99090432); // 16,777,216  ends 115,867,648

    // 0) convert ALL f32 tensors to bf16, one exact-grid launch (19072 blocks)
    cvt6<<<dim3(19072), 256, 0, stream>>>(
        hid,    hid_b,                          HIDDEN_ * S_LEN,
        q_a_w,  qkvaw_b,                        QR * HIDDEN_,
        kv_a_w, qkvaw_b + (size_t)QR * HIDDEN_, (KVR + DR) * HIDDEN_,
        q_b_w,  qbw_b,                          NH * DQK * QR,
        kv_b_w, kvbw_b,                         NH * 256 * KVR,
        o_w,    ow_b,                           HIDDEN_ * NH * DV);

    // 1) split-K x2: P0/P1 = hidden @ [q_a_w; kv_a_w]^T halves  [2048,2112] f32
    gemm_splitk<<<dim3((NQKV + 127) / 128, S_LEN / 128, 2), 256, 0, stream>>>(
        hid_b, qkvaw_b, P0, P1, S_LEN, NQKV, HIDDEN_ / 2, HIDDEN_);
    // 2+3) both RMSNorms (fused split-K combine) + k_pe passthrough
    rmsnorm2_k<<<dim3(S_LEN, 2), 256, 0, stream>>>(
        P0, P1, q_a_ln_w, q_n, kv_a_ln_w, ckv, kpe_b);
    // 4+5) qb = q_n @ q_b_w^T [2048,3072]  and  kvb = ckv @ kv_b_w^T [2048,4096]
    gemm_dual<<<dim3(32, S_LEN / 128, 2), 256, 0, stream>>>(
        q_n, qbw_b, qb,  S_LEN, NH * DQK, QR,
        ckv, kvbw_b, kvb, S_LEN, NH * 256, KVR);
    // 6) fused rope-repack (Q prescaled, K tiles) + V transpose (one launch)
    repack_fused<<<dim3(S_LEN + 1024), 256, 0, stream>>>(
        qb, kvb, kpe_b, Qb, Kb, Vtb);
    // 7) causal flash attention (L2-direct, no LDS staging)
    mla_attn<<<dim3(48, NH), 256, 0, stream>>>(Qb, Kb, Vtb, attnb, partb);
    // 7b) merge partials for strips 16..31
    attn_combine<<<dim3(16, NH), 256, 0, stream>>>(partb, attnb);
    // 8) split-K x2: out = attnb @ o_w^T  [2048,2048] f32 partials
    gemm_splitk<<<dim3(HIDDEN_ / 128, S_LEN / 128, 2), 256, 0, stream>>>(
        attnb, ow_b, PO0, PO1, S_LEN, HIDDEN_, HIDDEN_ / 2, HIDDEN_);
    // 8b) final combine -> d_out
    addf2<<<dim3((S_LEN * HIDDEN_) / 1024), 256, 0, stream>>>(
        PO0, PO1, (float*)d_out, S_LEN * HIDDEN_);
}

// Round 12
// 329.144 us; speedup vs baseline: 1.1512x; 1.1512x over previous
//
#include <hip/hip_runtime.h>
#include <stdint.h>

#define S_LEN 2048
#define HIDDEN_ 2048
#define NH 16
#define QR 1536
#define KVR 512
#define DN 128
#define DR 64
#define DQK 192
#define DV 128
#define NQKV 2112   // QR + KVR + DR

// per-head tile-image strides (u16 units)
#define KT_STRIDE 6144   // 32 rows x 192 cols = 12288 B
#define VT_STRIDE 4096   // 128 d x 32 s      =  8192 B

typedef __attribute__((ext_vector_type(8))) short bf16x8;
typedef __attribute__((ext_vector_type(4))) float f32x4;
typedef __attribute__((ext_vector_type(4))) unsigned short u16x4;
typedef unsigned short u16;
typedef unsigned int u32;

#define GLOAD_LDS16(g, l)                                                      \
    __builtin_amdgcn_global_load_lds(                                          \
        (const __attribute__((address_space(1))) void*)(g),                    \
        (__attribute__((address_space(3))) void*)(l), 16, 0, 0)

__device__ inline float bf2f(u16 x) {
    union { u32 u; float f; } v; v.u = ((u32)x) << 16; return v.f;
}
__device__ inline u16 f2bf(float f) {
    union { float f; u32 u; } v; v.f = f;
    u32 u = v.u;
    return (u16)((u + 0x7fffu + ((u >> 16) & 1u)) >> 16);
}

// ---------------------------------------------------------------------------
// cvt of ALL 6 f32 tensors -> bf16, one launch, exact flattened grid.
// Blocks: 4096+3072+1152+4608+2048+4096 = 19072. All sizes %1024==0.
// ---------------------------------------------------------------------------
__global__ void cvt6(const float* __restrict__ s0, u16* __restrict__ d0, int n0,
                     const float* __restrict__ s1, u16* __restrict__ d1, int n1,
                     const float* __restrict__ s2, u16* __restrict__ d2, int n2,
                     const float* __restrict__ s3, u16* __restrict__ d3, int n3,
                     const float* __restrict__ s4, u16* __restrict__ d4, int n4,
                     const float* __restrict__ s5, u16* __restrict__ d5, int n5)
{
    const int b0 = n0 >> 10, b1 = n1 >> 10, b2 = n2 >> 10, b3 = n3 >> 10,
              b4 = n4 >> 10;
    int gid = blockIdx.x;
    const float* src; u16* dst; int base;
    if (gid < b0)                     { src = s0; dst = d0; base = gid; }
    else if ((gid -= b0) < b1)        { src = s1; dst = d1; base = gid; }
    else if ((gid -= b1) < b2)        { src = s2; dst = d2; base = gid; }
    else if ((gid -= b2) < b3)        { src = s3; dst = d3; base = gid; }
    else if ((gid -= b3) < b4)        { src = s4; dst = d4; base = gid; }
    else                              { src = s5; dst = d5; base = gid - b4; }
    int i = base * 1024 + threadIdx.x * 4;
    float4 v = *(const float4*)(src + i);
    u16x4 o;
    o[0] = f2bf(v.x); o[1] = f2bf(v.y); o[2] = f2bf(v.z); o[3] = f2bf(v.w);
    *(u16x4*)(dst + i) = o;
}

// ---------------------------------------------------------------------------
// GEMM body (round-8 proven version): C[M,N] = A[M,Kloop] @ B[N,Kloop]^T,
// f32 accumulate, bf16 or f32 out. 128x128 tile, BK=32, global_load_lds.
// ---------------------------------------------------------------------------
__device__ __forceinline__
void gemm_body(const u16* __restrict__ A, const u16* __restrict__ B,
               void* __restrict__ Cv, int M, int N, int Kloop, int ld,
               int out_f32, int bx, int by)
{
    __shared__ u16 sA[128 * 32];
    __shared__ u16 sB[128 * 32];
    const int tid  = threadIdx.x;
    const int wave = tid >> 6;
    const int lane = tid & 63;
    const int l16  = lane & 15;
    const int quad = lane >> 4;
    const int m_blk = by * 128;
    const int n_blk = bx * 128;
    const int wm = (wave >> 1) * 64;
    const int wn = (wave & 1) * 64;

    const f32x4 zero4 = {0.f, 0.f, 0.f, 0.f};
    f32x4 acc[4][4];
#pragma unroll
    for (int i = 0; i < 4; i++)
#pragma unroll
        for (int j = 0; j < 4; j++) acc[i][j] = zero4;

    const int srow = lane >> 2;
    const int scol = (lane & 3) * 8;

    for (int k0 = 0; k0 < Kloop; k0 += 32) {
        __syncthreads();
#pragma unroll
        for (int p = 0; p < 2; p++) {
            const int rbase = wave * 32 + p * 16;
            const int row = rbase + srow;
            const u16* ga = A + (size_t)(m_blk + row) * ld + k0 + scol;
            GLOAD_LDS16(ga, &sA[rbase * 32]);
            int brow = n_blk + row; if (brow >= N) brow = N - 1;
            const u16* gb = B + (size_t)brow * ld + k0 + scol;
            GLOAD_LDS16(gb, &sB[rbase * 32]);
        }
        __syncthreads();

        bf16x8 af[4], bfr[4];
#pragma unroll
        for (int i = 0; i < 4; i++)
            af[i] = *(const bf16x8*)(sA + (wm + i * 16 + l16) * 32 + quad * 8);
#pragma unroll
        for (int j = 0; j < 4; j++)
            bfr[j] = *(const bf16x8*)(sB + (wn + j * 16 + l16) * 32 + quad * 8);
#pragma unroll
        for (int i = 0; i < 4; i++)
#pragma unroll
            for (int j = 0; j < 4; j++)
                acc[i][j] = __builtin_amdgcn_mfma_f32_16x16x32_bf16(
                    af[i], bfr[j], acc[i][j], 0, 0, 0);
    }

#pragma unroll
    for (int i = 0; i < 4; i++)
#pragma unroll
        for (int j = 0; j < 4; j++)
#pragma unroll
            for (int r = 0; r < 4; r++) {
                int mrow = m_blk + wm + i * 16 + quad * 4 + r;
                int ncol = n_blk + wn + j * 16 + l16;
                if (ncol < N) {
                    if (out_f32)
                        ((float*)Cv)[(size_t)mrow * N + ncol] = acc[i][j][r];
                    else
                        ((u16*)Cv)[(size_t)mrow * N + ncol] = f2bf(acc[i][j][r]);
                }
            }
}

// Split-K x2 GEMM: z selects K-half, writes f32 partials C0 / C1.
__global__ __launch_bounds__(256, 3)
void gemm_splitk(const u16* __restrict__ A, const u16* __restrict__ B,
                 float* __restrict__ C0, float* __restrict__ C1,
                 int M, int N, int Kh, int ld)
{
    float* C = blockIdx.z ? C1 : C0;
    gemm_body(A + (size_t)blockIdx.z * Kh, B + (size_t)blockIdx.z * Kh,
              C, M, N, Kh, ld, 1, blockIdx.x, blockIdx.y);
}

// Two independent GEMMs in one launch (z selects).
__global__ __launch_bounds__(256, 3)
void gemm_dual(const u16* A0, const u16* B0, u16* C0, int M0, int N0, int K0,
               const u16* A1, const u16* B1, u16* C1, int M1, int N1, int K1)
{
    if (blockIdx.z == 0) {
        if ((int)blockIdx.x >= (N0 + 127) / 128) return;
        gemm_body(A0, B0, C0, M0, N0, K0, K0, 0, blockIdx.x, blockIdx.y);
    } else {
        gemm_body(A1, B1, C1, M1, N1, K1, K1, 0, blockIdx.x, blockIdx.y);
    }
}

// ---------------------------------------------------------------------------
// Merged RMSNorm over split-K f32 partials (combine fused in).
// ---------------------------------------------------------------------------
__global__ void rmsnorm2_k(const float* __restrict__ P0, const float* __restrict__ P1,
                           const float* __restrict__ W0, u16* __restrict__ Y0,
                           const float* __restrict__ W1, u16* __restrict__ Y1,
                           u16* __restrict__ kpe)
{
    const int row = blockIdx.x;
    const float* p0 = P0 + (size_t)row * NQKV;
    const float* p1 = P1 + (size_t)row * NQKV;
    __shared__ float xbuf[QR];
    __shared__ float red[4];
    int off, len; const float* W; u16* Y;
    if (blockIdx.y == 0) { off = 0;  len = QR;  W = W0; Y = Y0 + (size_t)row * QR;  }
    else                 { off = QR; len = KVR; W = W1; Y = Y1 + (size_t)row * KVR; }
    float ss = 0.f;
    for (int i = threadIdx.x; i < len; i += 256) {
        float v = p0[off + i] + p1[off + i];
        xbuf[i] = v;
        ss += v * v;
    }
#pragma unroll
    for (int o = 32; o; o >>= 1) ss += __shfl_down(ss, o, 64);
    if ((threadIdx.x & 63) == 0) red[threadIdx.x >> 6] = ss;
    __syncthreads();
    float tot = red[0] + red[1] + red[2] + red[3];
    float inv = 1.0f / sqrtf(tot / (float)len + 1e-6f);
    for (int i = threadIdx.x; i < len; i += 256)
        Y[i] = f2bf(W[i] * xbuf[i] * inv);
    if (blockIdx.y == 1 && threadIdx.x < DR) {
        int i = threadIdx.x;
        kpe[(size_t)row * DR + i] = f2bf(p0[QR + KVR + i] + p1[QR + KVR + i]);
    }
}

// ---------------------------------------------------------------------------
// FUSED repack: blocks 0..2047 do RoPE+repack (Q prescaled by scale/ln2,
// K tile images); blocks 2048..3071 do V transpose -> tile images.
// ---------------------------------------------------------------------------
__global__ void repack_fused(const u16* __restrict__ q,      // [S][H*192]
                             const u16* __restrict__ kvb,    // [S][H*256]
                             const u16* __restrict__ kpe_b,  // [S][64]
                             u16* __restrict__ Q, u16* __restrict__ Kf,
                             u16* __restrict__ Vt)
{
    __shared__ __align__(16) char smem[64 * 72 * 2];   // 9216 B, both branches
    const int bid = blockIdx.x;
    const int t = threadIdx.x;

    if (bid < S_LEN) {
        // ---------------- RoPE + Q/K repack ----------------
        float* cs = (float*)smem;            // [64]
        float* sn = cs + 64;                 // [64]
        u16* kpe_r = (u16*)(sn + 64);        // [64]
        const float QSC = 0.07216878364870323f * 1.4426950408889634f;
        const int s = bid;
        const float pos = (float)s;
        if (t < 64) {
            int jf = t & 31;
            float freq = powf(10000.f, -(float)(2 * jf) / 64.f);
            float ang = pos * freq;
            cs[t] = cosf(ang);
            sn[t] = sinf(ang);
        }
        __syncthreads();
        if (t < 64) {
            int j = t;
            float x = bf2f(kpe_b[(size_t)s * DR + j]);
            float other = (j < 32) ? -bf2f(kpe_b[(size_t)s * DR + j + 32])
                                   :  bf2f(kpe_b[(size_t)s * DR + j - 32]);
            kpe_r[j] = f2bf(x * cs[j] + other * sn[j]);
        }
        __syncthreads();

        for (int idx = t; idx < NH * 24; idx += 256) {
            const int h  = idx / 24;
            const int cg = idx % 24;
            const int d0v = cg * 8;
            const size_t qbase = (size_t)s * (NH * DQK) + h * DQK;
            bf16x8 qv, kv;
            if (d0v < DN) {
                bf16x8 qr = *(const bf16x8*)(q + qbase + d0v);
#pragma unroll
                for (int e = 0; e < 8; e++)
                    qv[e] = (short)f2bf(bf2f((u16)qr[e]) * QSC);
                kv = *(const bf16x8*)(kvb + (size_t)s * (NH * 256) + h * 256 + d0v);
            } else {
                const int j0 = d0v - DN;
#pragma unroll
                for (int e = 0; e < 8; e++) {
                    int j = j0 + e;
                    float x = bf2f(q[qbase + DN + j]);
                    float other = (j < 32) ? -bf2f(q[qbase + DN + j + 32])
                                           :  bf2f(q[qbase + DN + j - 32]);
                    qv[e] = (short)f2bf((x * cs[j] + other * sn[j]) * QSC);
                    kv[e] = (short)kpe_r[j];
                }
            }
            *(bf16x8*)&Q[((size_t)h * S_LEN + s) * DQK + d0v] = qv;
            const size_t koff = (size_t)(h * 64 + (s >> 5)) * KT_STRIDE
                              + (size_t)(cg * 32 + (s & 31)) * 8;
            *(bf16x8*)&Kf[koff] = kv;
        }
    } else {
        // ---------------- V transpose -> tile images ----------------
        u16 (*tile)[72] = (u16(*)[72])smem;
        const int r   = bid - S_LEN;          // 0..1023
        const int h   = r >> 6;
        const int rem = r & 63;
        const int s0  = (rem >> 1) * 64;
        const int d0  = (rem & 1) * 64;
#pragma unroll
        for (int p = 0; p < 2; p++) {
            int c = p * 256 + t;
            int rr = c >> 3, col = (c & 7) * 8;
            *(bf16x8*)&tile[rr][col] =
                *(const bf16x8*)&kvb[(size_t)(s0 + rr) * (NH * 256) + h * 256 + 128 + d0 + col];
        }
        __syncthreads();
#pragma unroll
        for (int p = 0; p < 2; p++) {
            int c = p * 256 + t;
            int dr = c >> 3, sc = (c & 7) * 8;
            bf16x8 v;
#pragma unroll
            for (int j = 0; j < 8; j++) v[j] = (short)tile[sc + j][dr];
            const int s_abs   = s0 + sc;
            const int kt      = s_abs >> 5;
            const int schunk  = (s_abs & 31) >> 3;
            const size_t voff = (size_t)(h * 64 + kt) * VT_STRIDE
                              + (size_t)(schunk * 128 + (d0 + dr)) * 8;
            *(bf16x8*)&Vt[voff] = v;
        }
    }
}

// ---------------------------------------------------------------------------
// Causal flash attention, round-4/8 proven schedule (balanced durations):
// grid (48, NH), XCD head-affinity swizzle; per-CU triplet {b, 16+b, 32+b}
// with lengths {32, 2b+2, 32-2b} (chunk-1 ascending s=bx) -> 66 tiles/CU.
// LDS-staged K/V (cooperative prefetch; L2-direct variant was 2x slower —
// per-lane load latency lands on the MFMA critical path). Softmax in log2
// domain; bpermute P-exchange; deferred row-sum; defer-max;
// v_cvt_pk_bf16_f32 packing; setprio around MFMA clusters.
// ---------------------------------------------------------------------------
__global__ __launch_bounds__(256, 3)
void mla_attn(const u16* __restrict__ Q, const u16* __restrict__ Kf,
              const u16* __restrict__ Vt, u16* __restrict__ attn,
              float* __restrict__ part)
{
    const int lin = blockIdx.x + 48 * blockIdx.y;
    const int h   = ((lin & 7) << 1) | ((lin >> 3) & 1);
    const int bx  = lin >> 4;

    int s, tb, te, cIdx; bool direct;
    if (bx < 16)      { s = 16 + bx; tb = 0;  te = 32;        cIdx = 0; direct = false; }
    else if (bx < 32) { s = bx;      tb = 32; te = 2 * s + 2; cIdx = 1; direct = false; }
    else              { s = 47 - bx; tb = 0;  te = 2 * s + 2; cIdx = 0; direct = true;  }

    const int wave  = threadIdx.x >> 6;
    const int lane  = threadIdx.x & 63;
    const int l16   = lane & 15;
    const int quad  = lane >> 4;
    const int q0    = s * 64 + wave * 16;
    const int qrow  = q0 + l16;

    const u16* Qh  = Q  + (size_t)h * S_LEN * DQK;
    const u16* Kh  = Kf + (size_t)h * 64 * KT_STRIDE;
    const u16* Vth = Vt + (size_t)h * 64 * VT_STRIDE;

    __shared__ u16 sK[2][24 * 32 * 8];    // 2 x 12 KB
    __shared__ u16 sV[2][4 * 128 * 8];    // 2 x  8 KB

    bf16x8 qf[6];
#pragma unroll
    for (int st = 0; st < 6; st++)
        qf[st] = *(const bf16x8*)(Qh + (size_t)qrow * DQK + st * 32 + quad * 8);

    const f32x4 zero4 = {0.f, 0.f, 0.f, 0.f};
    f32x4 oacc[8];
#pragma unroll
    for (int t = 0; t < 8; t++) oacc[t] = zero4;
    float mrow = -INFINITY, lrow = 0.f;   // log2 domain; lrow per-lane partial

    auto stage = [&](int buf, int kt) {
        const u16* kp = Kh + (size_t)kt * KT_STRIDE;
#pragma unroll
        for (int g = 0; g < 3; g++)
            GLOAD_LDS16(kp + (g * 256 + wave * 64 + lane) * 8,
                        &sK[buf][(g * 256 + wave * 64) * 8]);
        const u16* vp = Vth + (size_t)kt * VT_STRIDE;
#pragma unroll
        for (int g = 0; g < 2; g++)
            GLOAD_LDS16(vp + (g * 256 + wave * 64 + lane) * 8,
                        &sV[buf][(g * 256 + wave * 64) * 8]);
    };

    stage(0, tb);   // prologue

    for (int kt = tb; kt < te; kt++) {
        const int c0  = kt * 32;
        const int cur = (kt - tb) & 1;
        __syncthreads();
        if (kt + 1 < te) stage(cur ^ 1, kt + 1);

        if (c0 <= q0 + 15) {
            f32x4 s0 = zero4, s1 = zero4;
            __builtin_amdgcn_s_setprio(1);
#pragma unroll
            for (int st = 0; st < 6; st++) {
                bf16x8 k0 = *(const bf16x8*)&sK[cur][((st * 4 + quad) * 32 + l16) * 8];
                bf16x8 k1 = *(const bf16x8*)&sK[cur][((st * 4 + quad) * 32 + 16 + l16) * 8];
                s0 = __builtin_amdgcn_mfma_f32_16x16x32_bf16(k0, qf[st], s0, 0, 0, 0);
                s1 = __builtin_amdgcn_mfma_f32_16x16x32_bf16(k1, qf[st], s1, 0, 0, 0);
            }
            __builtin_amdgcn_s_setprio(0);
            bf16x8 vfr[8];
#pragma unroll
            for (int t = 0; t < 8; t++)
                vfr[t] = *(const bf16x8*)&sV[cur][(quad * 128 + t * 16 + l16) * 8];

            const bool full = (c0 + 31 <= q0);
            float v0[4], v1[4];
#pragma unroll
            for (int r = 0; r < 4; r++) {
                v0[r] = s0[r];
                v1[r] = s1[r];
                if (!full) {
                    if (c0 + quad * 4 + r > qrow)      v0[r] = -INFINITY;
                    if (c0 + 16 + quad * 4 + r > qrow) v1[r] = -INFINITY;
                }
            }
            float lm = fmaxf(fmaxf(fmaxf(v0[0], v0[1]), fmaxf(v0[2], v0[3])),
                             fmaxf(fmaxf(v1[0], v1[1]), fmaxf(v1[2], v1[3])));
            lm = fmaxf(lm, __shfl_xor(lm, 16, 64));
            lm = fmaxf(lm, __shfl_xor(lm, 32, 64));

            // defer-max: skip rescale while tile max within +8/ln2 of m.
            float mref;
            if (__all(lm <= mrow + 11.5416f)) {
                mref = mrow;               // p <= 2^11.54 = e^8, bf16-safe
            } else {
                mref = fmaxf(mrow, lm);
                const float alpha = __builtin_amdgcn_exp2f(mrow - mref);
#pragma unroll
                for (int t = 0; t < 8; t++) oacc[t] *= alpha;
                lrow *= alpha;
                mrow = mref;
            }

            float p0[4], p1[4], rs = 0.f;
#pragma unroll
            for (int r = 0; r < 4; r++) {
                p0[r] = __builtin_amdgcn_exp2f(v0[r] - mref);
                p1[r] = __builtin_amdgcn_exp2f(v1[r] - mref);
                rs += p0[r] + p1[r];
            }
            lrow += rs;   // per-lane partial; reduced in epilogue

            // P pack via v_cvt_pk_bf16_f32 (RTNE = f2bf pair, 1 inst each)
            u32 A0, A1, B0, B1;
            asm("v_cvt_pk_bf16_f32 %0, %1, %2" : "=v"(A0) : "v"(p0[0]), "v"(p0[1]));
            asm("v_cvt_pk_bf16_f32 %0, %1, %2" : "=v"(A1) : "v"(p0[2]), "v"(p0[3]));
            asm("v_cvt_pk_bf16_f32 %0, %1, %2" : "=v"(B0) : "v"(p1[0]), "v"(p1[1]));
            asm("v_cvt_pk_bf16_f32 %0, %1, %2" : "=v"(B1) : "v"(p1[2]), "v"(p1[3]));
            const int a0 = (((quad & 1) << 5) + l16) << 2;
            const int a1 = a0 + 64;
            u32 Y0 = (u32)__builtin_amdgcn_ds_bpermute(a0, (int)A0);
            u32 Y1 = (u32)__builtin_amdgcn_ds_bpermute(a0, (int)A1);
            u32 Y2 = (u32)__builtin_amdgcn_ds_bpermute(a1, (int)A0);
            u32 Y3 = (u32)__builtin_amdgcn_ds_bpermute(a1, (int)A1);
            u32 Z0 = (u32)__builtin_amdgcn_ds_bpermute(a0, (int)B0);
            u32 Z1 = (u32)__builtin_amdgcn_ds_bpermute(a0, (int)B1);
            u32 Z2 = (u32)__builtin_amdgcn_ds_bpermute(a1, (int)B0);
            u32 Z3 = (u32)__builtin_amdgcn_ds_bpermute(a1, (int)B1);
            const bool useA = quad < 2;
            union { u32 w[4]; bf16x8 v; } pf;
            pf.w[0] = useA ? Y0 : Z0;
            pf.w[1] = useA ? Y1 : Z1;
            pf.w[2] = useA ? Y2 : Z2;
            pf.w[3] = useA ? Y3 : Z3;
            bf16x8 pfrag = pf.v;

            __builtin_amdgcn_s_setprio(1);
#pragma unroll
            for (int t = 0; t < 8; t++)
                oacc[t] = __builtin_amdgcn_mfma_f32_16x16x32_bf16(vfr[t], pfrag,
                                                                  oacc[t], 0, 0, 0);
            __builtin_amdgcn_s_setprio(0);
        }
    }

    // finish deferred row-sum (partials live per-quad)
    float lsum = lrow;
    lsum += __shfl_xor(lsum, 16, 64);
    lsum += __shfl_xor(lsum, 32, 64);

    if (direct) {
        const float linv = 1.0f / lsum;
#pragma unroll
        for (int t = 0; t < 8; t++) {
            u16x4 ov;
#pragma unroll
            for (int r = 0; r < 4; r++) ov[r] = f2bf(oacc[t][r] * linv);
            *(u16x4*)&attn[(size_t)qrow * (NH * DV) + h * DV + t * 16 + quad * 4] = ov;
        }
    } else {
        // partial record: 8320 f32 = O[64][128] ++ m[64] ++ l[64] (m in log2)
        float* pout = part + ((size_t)(h * 16 + (s - 16)) * 2 + cIdx) * 8320;
        const int rowl = wave * 16 + l16;
#pragma unroll
        for (int t = 0; t < 8; t++) {
            float4 ov = {oacc[t][0], oacc[t][1], oacc[t][2], oacc[t][3]};
            *(float4*)&pout[(size_t)rowl * 128 + t * 16 + quad * 4] = ov;
        }
        if (quad == 0) {
            pout[8192 + rowl] = mrow;
            pout[8256 + rowl] = lsum;
        }
    }
}

// ---------------------------------------------------------------------------
// Merge the two split-K partials for strips s=16..31 (m in log2 domain).
// ---------------------------------------------------------------------------
__global__ void attn_combine(const float* __restrict__ part, u16* __restrict__ attn)
{
    const int h = blockIdx.y, sIdx = blockIdx.x;
    const int s = 16 + sIdx;
    const float* p0 = part + ((size_t)(h * 16 + sIdx) * 2 + 0) * 8320;
    const float* p1 = p0 + 8320;
    for (int e = threadIdx.x; e < 8192; e += 256) {
        int row = e >> 7, d = e & 127;
        float m0 = p0[8192 + row], m1 = p1[8192 + row];
        float l0 = p0[8256 + row], l1 = p1[8256 + row];
        float M  = fmaxf(m0, m1);
        float w0 = __builtin_amdgcn_exp2f(m0 - M);
        float w1 = __builtin_amdgcn_exp2f(m1 - M);
        float o  = (w0 * p0[e] + w1 * p1[e]) / (w0 * l0 + w1 * l1);
        attn[(size_t)(s * 64 + row) * (NH * DV) + h * DV + d] = f2bf(o);
    }
}

// ---------------------------------------------------------------------------
// f32 a + b -> f32 out (final split-K combine for the output GEMM).
// ---------------------------------------------------------------------------
__global__ void addf2(const float* __restrict__ a, const float* __restrict__ b,
                      float* __restrict__ o, int n)
{
    int i = (blockIdx.x * 256 + threadIdx.x) * 4;
    if (i + 3 < n) {
        float4 va = *(const float4*)(a + i);
        float4 vb = *(const float4*)(b + i);
        float4 vo = {va.x + vb.x, va.y + vb.y, va.z + vb.z, va.w + vb.w};
        *(float4*)(o + i) = vo;
    }
}

// ---------------------------------------------------------------------------
extern "C" void kernel_launch(void* const* d_in, const int* in_sizes, int n_in,
                              void* d_out, int out_size, void* d_ws, size_t ws_size,
                              hipStream_t stream)
{
    const float* hid      = (const float*)d_in[0];
    // d_in[1] = position_ids (== arange(s)); sequence index used directly.
    const float* q_a_w    = (const float*)d_in[2];
    const float* q_a_ln_w = (const float*)d_in[3];
    const float* q_b_w    = (const float*)d_in[4];
    const float* kv_a_w   = (const float*)d_in[5];
    const float* kv_a_ln_w= (const float*)d_in[6];
    const float* kv_b_w   = (const float*)d_in[7];
    const float* o_w      = (const float*)d_in[8];

    char* base = (char*)d_ws;
    // -------- static (whole-call lifetime) --------
    u16* qkvaw_b = (u16*)(base + 0);          //  8,650,752  [2112,2048]
    u16* qbw_b   = (u16*)(base + 8650752);    //  9,437,184  [3072,1536]
    u16* kvbw_b  = (u16*)(base + 18087936);   //  4,194,304  [4096,512]
    u16* ow_b    = (u16*)(base + 22282240);   //  8,388,608  [2048,2048]
    u16* hid_b   = (u16*)(base + 30670848);   //  8,388,608  (dead after gemm1)
    // -------- dynamic (lifetime-overlaid) --------
    float* P0    = (float*)(base + 39059456); // 17,301,504  gemm1 K-half 0 (f32)
    float* P1    = (float*)(base + 56360960); // 17,301,504  gemm1 K-half 1 (f32)
    u16* q_n     = (u16*)(base + 73662464);   //  6,291,456  [2048,1536]
    u16* ckv     = (u16*)(base + 79953920);   //  2,097,152  [2048,512]
    u16* kpe_b   = (u16*)(base + 82051072);   //    262,144  [2048,64]
    u16* qb      = (u16*)(base + 82313216);   // 12,582,912  [2048,3072]
    u16* kvb     = (u16*)(base + 94896128);   // 16,777,216  [2048,4096]
    u16* Qb      = (u16*)(base + 39059456);   // 12,582,912  over dead P0
    u16* Kb      = (u16*)(base + 51642368);   // 12,582,912  tile images
    u16* Vtb     = (u16*)(base + 64225280);   //  8,388,608  tile images
    u16* attnb   = (u16*)(base + 72613888);   //  8,388,608  over dead q_n/ckv
    float* partb = (float*)(base + 94896128); // 17,039,360  over dead kvb
    float* PO0   = (float*)(base + 82313216); // 16,777,216  over dead qb/partb
    float* PO1   = (float*)(base + 99090432); // 16,777,216  ends 115,867,648

    // 0) convert ALL f32 tensors to bf16, one exact-grid launch (19072 blocks)
    cvt6<<<dim3(19072), 256, 0, stream>>>(
        hid,    hid_b,                          HIDDEN_ * S_LEN,
        q_a_w,  qkvaw_b,                        QR * HIDDEN_,
        kv_a_w, qkvaw_b + (size_t)QR * HIDDEN_, (KVR + DR) * HIDDEN_,
        q_b_w,  qbw_b,                          NH * DQK * QR,
        kv_b_w, kvbw_b,                         NH * 256 * KVR,
        o_w,    ow_b,                           HIDDEN_ * NH * DV);

    // 1) split-K x2: P0/P1 = hidden @ [q_a_w; kv_a_w]^T halves  [2048,2112] f32
    gemm_splitk<<<dim3((NQKV + 127) / 128, S_LEN / 128, 2), 256, 0, stream>>>(
        hid_b, qkvaw_b, P0, P1, S_LEN, NQKV, HIDDEN_ / 2, HIDDEN_);
    // 2+3) both RMSNorms (fused split-K combine) + k_pe passthrough
    rmsnorm2_k<<<dim3(S_LEN, 2), 256, 0, stream>>>(
        P0, P1, q_a_ln_w, q_n, kv_a_ln_w, ckv, kpe_b);
    // 4+5) qb = q_n @ q_b_w^T [2048,3072]  and  kvb = ckv @ kv_b_w^T [2048,4096]
    gemm_dual<<<dim3(32, S_LEN / 128, 2), 256, 0, stream>>>(
        q_n, qbw_b, qb,  S_LEN, NH * DQK, QR,
        ckv, kvbw_b, kvb, S_LEN, NH * 256, KVR);
    // 6) fused rope-repack (Q prescaled, K tiles) + V transpose (one launch)
    repack_fused<<<dim3(S_LEN + 1024), 256, 0, stream>>>(
        qb, kvb, kpe_b, Qb, Kb, Vtb);
    // 7) causal flash attention (round-4/8 balanced schedule) -> attnb + partials
    mla_attn<<<dim3(48, NH), 256, 0, stream>>>(Qb, Kb, Vtb, attnb, partb);
    // 7b) merge partials for strips 16..31
    attn_combine<<<dim3(16, NH), 256, 0, stream>>>(partb, attnb);
    // 8) split-K x2: out = attnb @ o_w^T  [2048,2048] f32 partials
    gemm_splitk<<<dim3(HIDDEN_ / 128, S_LEN / 128, 2), 256, 0, stream>>>(
        attnb, ow_b, PO0, PO1, S_LEN, HIDDEN_, HIDDEN_ / 2, HIDDEN_);
    // 8b) final combine -> d_out
    addf2<<<dim3((S_LEN * HIDDEN_) / 1024), 256, 0, stream>>>(
        PO0, PO1, (float*)d_out, S_LEN * HIDDEN_);
}